// Round 19
// baseline (71.469 us; speedup 1.0000x reference)
//
#include <hip/hip_runtime.h>
#include <hip/hip_bf16.h>

#define B_ 4
#define L_ 2048
#define D_ 512
#define H_ 8
#define DK_ 64

typedef __bf16 bf16x8 __attribute__((ext_vector_type(8)));
typedef float f32x4 __attribute__((ext_vector_type(4)));
typedef unsigned short u16;
typedef unsigned short u16x8 __attribute__((ext_vector_type(8)));

template <bool V> struct BoolC { static constexpr bool value = V; };

__device__ __forceinline__ float b2f(unsigned short u) {
  union { unsigned int i; float f; } c; c.i = ((unsigned int)u) << 16; return c.f;
}
__device__ __forceinline__ unsigned short f2b(float f) {
  union { float f; unsigned int i; } c; c.f = f;
  unsigned int x = c.i;
  unsigned int r = x + 0x7fffu + ((x >> 16) & 1u);   // RNE
  return (unsigned short)(r >> 16);
}

// ---------------- fp32 -> bf16 convert: 4 weights + fused bias pack (x handled in gemm_qkv) ----------------
__global__ __launch_bounds__(256) void cvt_w(
    const float* __restrict__ W0, const float* __restrict__ W1,
    const float* __restrict__ W2, const float* __restrict__ W3,
    const float* __restrict__ bq, const float* __restrict__ bk, const float* __restrict__ bv,
    u16* __restrict__ O0, u16* __restrict__ O1, u16* __restrict__ O2, u16* __restrict__ O3,
    float* __restrict__ bcomb) {
  int bid = blockIdx.x;
  int t = threadIdx.x;
  if (bid == 1024) {                      // pack fused bias [1536]
#pragma unroll
    for (int e = 0; e < 6; ++e) {
      int idx = t + e * 256;
      float v = (idx < 512) ? bq[idx] : (idx < 1024) ? bk[idx - 512] : bv[idx - 1024];
      bcomb[idx] = v;
    }
    return;
  }
  int z = bid >> 8;                       // weights: 65,536 float4s each
  const float* in = (z == 0) ? W0 : (z == 1) ? W1 : (z == 2) ? W2 : W3;
  u16* out = (z == 0) ? O0 : (z == 1) ? O1 : (z == 2) ? O2 : O3;
  int i = (bid & 255) * 256 + t;
  float4 v = reinterpret_cast<const float4*>(in)[i];
  ushort4 o;
  o.x = f2b(v.x); o.y = f2b(v.y); o.z = f2b(v.z); o.w = f2b(v.w);
  reinterpret_cast<ushort4*>(out)[i] = o;
}

// ---------------- fused QKV GEMM: [8192x512](f32, converted in-staging) @ [1536x512]^T + bias ----------------
// A read directly from x (f32) and converted during LDS staging (fuses the cvt pass).
// B staged via global_load_lds (issued first: DMA overlaps A's register work).
// Q pre-scaled by 0.125 (exact power-of-two).
__global__ __launch_bounds__(256, 4) void gemm_qkv(
    const float* __restrict__ X, const u16* __restrict__ Bw,
    const float* __restrict__ bias, u16* __restrict__ QKVB)
{
  __shared__ __align__(16) u16 Al[64][64];
  __shared__ __align__(16) u16 Bl[128][64];
  const int t = threadIdx.x;
  // XCD swizzle: 1536 wgs = 8 xcds x 192
  const int wg = (blockIdx.x & 7) * 192 + (blockIdx.x >> 3);
  const int mt = wg / 12, nt = wg - mt * 12;
  const int m0 = mt * 64, n0c = nt * 128;
  const int z = n0c >> 9;
  u16* Obf = QKVB + (size_t)z * 4194304;

  const int w = t >> 6, lane = t & 63;
  const int wr = (w >> 1) * 32, wc = (w & 1) * 64;
  const int lr = lane & 15, lk = (lane >> 4) * 8;
  const int srow = (lane >> 3), scol = (lane & 7) * 8;

  f32x4 acc[2][4] = {};

  for (int ks = 0; ks < 8; ++ks) {
    const int k0 = ks * 64;
    // ---- B: async DMA to LDS (issue first) ----
#pragma unroll
    for (int c = 0; c < 4; ++c) {
      const int ci = w * 4 + c;
      const u16* gb = Bw + (size_t)(n0c + ci * 8 + srow) * 512 + k0 + scol;
      __builtin_amdgcn_global_load_lds(
          (const __attribute__((address_space(1))) void*)gb,
          (__attribute__((address_space(3))) void*)&Bl[ci * 8][0], 16, 0, 0);
    }
    // ---- A: f32 load + convert + LDS write (overlaps B's DMA) ----
#pragma unroll
    for (int c = 0; c < 2; ++c) {
      const int ci = w * 2 + c;
      const float* gx = X + (size_t)(m0 + ci * 8 + srow) * 512 + k0 + scol;
      float4 a0 = *reinterpret_cast<const float4*>(gx);
      float4 a1 = *reinterpret_cast<const float4*>(gx + 4);
      u16x8 u;
      u[0] = f2b(a0.x); u[1] = f2b(a0.y); u[2] = f2b(a0.z); u[3] = f2b(a0.w);
      u[4] = f2b(a1.x); u[5] = f2b(a1.y); u[6] = f2b(a1.z); u[7] = f2b(a1.w);
      *reinterpret_cast<u16x8*>(&Al[ci * 8 + srow][scol]) = u;
    }
    __syncthreads();
#pragma unroll
    for (int kk = 0; kk < 64; kk += 32) {
      bf16x8 af[2], bfr[4];
#pragma unroll
      for (int m = 0; m < 2; ++m)
        af[m] = *reinterpret_cast<const bf16x8*>(&Al[wr + m * 16 + lr][kk + lk]);
#pragma unroll
      for (int n = 0; n < 4; ++n)
        bfr[n] = *reinterpret_cast<const bf16x8*>(&Bl[wc + n * 16 + lr][kk + lk]);
#pragma unroll
      for (int m = 0; m < 2; ++m)
#pragma unroll
        for (int n = 0; n < 4; ++n)
          acc[m][n] = __builtin_amdgcn_mfma_f32_16x16x32_bf16(af[m], bfr[n], acc[m][n], 0, 0, 0);
    }
    __syncthreads();
  }

  const float qscale = (z == 0) ? 0.125f : 1.0f;     // block-uniform
  const int rb = (lane >> 4) * 4;
#pragma unroll
  for (int m = 0; m < 2; ++m) {
#pragma unroll
    for (int n = 0; n < 4; ++n) {
#pragma unroll
      for (int r = 0; r < 4; ++r) {
        int row = m0 + wr + m * 16 + rb + r;
        int colc = n0c + wc + n * 16 + lr;
        float v = (acc[m][n][r] + bias[colc]) * qscale;
        int b = row >> 11, l = row & 2047, h = (colc >> 6) & 7, dk = colc & 63;
        Obf[(((size_t)(b * 8 + h)) * 2048 + l) * 64 + dk] = f2b(v);
      }
    }
  }
}

// ---------------- windowed attention via MFMA (v5) ----------------
__global__ __launch_bounds__(256, 4) void attn_mfma(
    const u16* __restrict__ Qb, const u16* __restrict__ Kb, const u16* __restrict__ Vb,
    u16* __restrict__ AO,
    u16* __restrict__ pband)
{
  __shared__ __align__(16) u16 VT[64][136];
  __shared__ __align__(16) u16 Pl[4][16][104];
  __shared__ __align__(16) u16 Ol[4][16][72];

  const int t = threadIdx.x;
  const int blk = blockIdx.x;
  const int qt = blk & 31, bh = blk >> 5;
  const int b = bh >> 3, h = bh & 7;
  const int q0 = qt * 64;
  const int kbase0 = q0 - 32;
  const u16* Kp = Kb + (size_t)bh * L_ * 64;
  const u16* Vp = Vb + (size_t)bh * L_ * 64;
  const u16* Qp = Qb + (size_t)bh * L_ * 64;

  const int w = t >> 6, lane = t & 63;
  const int g = lane >> 4, ql16 = lane & 15;
  const int q = q0 + 16 * w + ql16;

  auto body = [&](auto edgec) {
    constexpr bool EDGE = decltype(edgec)::value;

    u16x8 vstage[4];
#pragma unroll
    for (int i = 0; i < 4; ++i) {
      int seg = i * 256 + t;
      int jb = seg >> 3, dk0 = (seg & 7) * 8;
      int src = kbase0 + jb;
      if (EDGE) src = src < 0 ? 0 : (src >= L_ ? L_ - 1 : src);
      vstage[i] = *reinterpret_cast<const u16x8*>(Vp + (size_t)src * 64 + dk0);
    }
    bf16x8 qf[2];
#pragma unroll
    for (int kc = 0; kc < 2; ++kc)
      qf[kc] = *reinterpret_cast<const bf16x8*>(Qp + (size_t)q * 64 + 32 * kc + 8 * g);

#pragma unroll
    for (int i = 0; i < 4; ++i) {
      int seg = i * 256 + t;
      int jb = seg >> 3, dk0 = (seg & 7) * 8;
      int jp = jb ^ dk0;
#pragma unroll
      for (int e = 0; e < 8; ++e)
        VT[dk0 + e][jp] = vstage[i][e];
    }

    bf16x8 kf[5][2];
#pragma unroll
    for (int f = 0; f < 5; ++f) {
      int row = kbase0 + 16 * w + 16 * f + ql16;
      if (EDGE) row = row < 0 ? 0 : (row >= L_ ? L_ - 1 : row);
#pragma unroll
      for (int kc = 0; kc < 2; ++kc)
        kf[f][kc] = *reinterpret_cast<const bf16x8*>(Kp + (size_t)row * 64 + 32 * kc + 8 * g);
    }

    f32x4 sacc[5] = {};
    __builtin_amdgcn_s_setprio(1);
#pragma unroll
    for (int kc = 0; kc < 2; ++kc)
#pragma unroll
      for (int f = 0; f < 5; ++f)
        sacc[f] = __builtin_amdgcn_mfma_f32_16x16x32_bf16(kf[f][kc], qf[kc], sacc[f], 0, 0, 0);
    __builtin_amdgcn_s_setprio(0);

    float mx = -1e30f;
#pragma unroll
    for (int f = 0; f < 5; ++f) {
#pragma unroll
      for (int r = 0; r < 4; ++r) {
        int jl = 16 * f + 4 * g + r;
        int jj = jl - ql16;
        bool valid;
        if constexpr (EDGE) {
          int key = kbase0 + 16 * w + jl;
          valid = (jj >= 0) && (jj <= 64) && (key >= 0) && (key < L_);
        } else {
          valid = (jj >= 0) && (jj <= 64);
        }
        float v = valid ? sacc[f][r] : -1e30f;
        sacc[f][r] = v;
        mx = fmaxf(mx, v);
      }
    }
    mx = fmaxf(mx, __shfl_xor(mx, 16, 64));
    mx = fmaxf(mx, __shfl_xor(mx, 32, 64));
    float den = 0.f;
#pragma unroll
    for (int f = 0; f < 5; ++f)
#pragma unroll
      for (int r = 0; r < 4; ++r) {
        float e = __expf(sacc[f][r] - mx);
        sacc[f][r] = e; den += e;
      }
    den += __shfl_xor(den, 16, 64);
    den += __shfl_xor(den, 32, 64);
    const float inv = 1.0f / den;

#pragma unroll
    for (int f = 0; f < 5; ++f) {
      ushort4 pk;
#pragma unroll
      for (int r = 0; r < 4; ++r)
        reinterpret_cast<u16*>(&pk)[r] = f2b(sacc[f][r] * inv);
      *reinterpret_cast<ushort4*>(&Pl[w][ql16][16 * f + 4 * g]) = pk;
    }
    {
      ushort4 z; z.x = z.y = z.z = z.w = 0;
      *reinterpret_cast<ushort4*>(&Pl[w][ql16][80 + 4 * g]) = z;
    }

    {
      u16* pbg = pband + ((size_t)bh * L_ + q0 + 16 * w) * 80;
#pragma unroll
      for (int i = 0; i < 3; ++i) {
        int seg = i * 64 + lane;
        if (seg < 160) {
          int r16 = seg / 10, c = seg - r16 * 10;
          *reinterpret_cast<uint4*>(pbg + (size_t)r16 * 80 + 8 * c) =
              *reinterpret_cast<const uint4*>(&Pl[w][r16][8 * c]);
        }
      }
    }

    __syncthreads();

    f32x4 oacc[4] = {};
    __builtin_amdgcn_s_setprio(1);
#pragma unroll
    for (int kc = 0; kc < 3; ++kc) {
      bf16x8 pf = *reinterpret_cast<const bf16x8*>(&Pl[w][ql16][32 * kc + 8 * g]);
#pragma unroll
      for (int m = 0; m < 4; ++m) {
        int dk = 16 * m + ql16;
        int jb = 16 * w + 32 * kc + 8 * g;
        if (jb > 120) jb = 120;
        bf16x8 vf = *reinterpret_cast<const bf16x8*>(&VT[dk][jb ^ (dk & 56)]);
        oacc[m] = __builtin_amdgcn_mfma_f32_16x16x32_bf16(vf, pf, oacc[m], 0, 0, 0);
      }
    }
    __builtin_amdgcn_s_setprio(0);

#pragma unroll
    for (int m = 0; m < 4; ++m) {
      ushort4 ok;
#pragma unroll
      for (int r = 0; r < 4; ++r) reinterpret_cast<u16*>(&ok)[r] = f2b(oacc[m][r]);
      *reinterpret_cast<ushort4*>(&Ol[w][ql16][16 * m + 4 * g]) = ok;
    }
#pragma unroll
    for (int i = 0; i < 2; ++i) {
      int seg = i * 64 + lane;
      int r16 = seg >> 3, ck = seg & 7;
      *reinterpret_cast<uint4*>(AO + ((size_t)(b * L_ + q0 + 16 * w + r16)) * 512 + h * 64 + ck * 8) =
          *reinterpret_cast<const uint4*>(&Ol[w][r16][ck * 8]);
    }
  };

  if (qt >= 1 && qt <= 30) body(BoolC<false>{});
  else body(BoolC<true>{});
}

// ---------------- fused tail: out-proj GEMM (512 blocks) + mean (2048 blocks) ----------------
__global__ __launch_bounds__(256, 4) void tail_fused(
    const u16* __restrict__ A,            // AO bf16 [8192][512]
    const u16* __restrict__ Bw,           // WOB bf16 [512][512]
    const float* __restrict__ bias,       // bo [512]
    float* __restrict__ Of,               // out0 [8192][512] f32
    const u16* __restrict__ pband,        // [B*H*L][80] bf16 (jl layout)
    float* __restrict__ out1)             // [B*L][2048] f32
{
  __shared__ __align__(16) u16 Al[128][64];
  __shared__ __align__(16) u16 Bl[64][64];
  const int t = threadIdx.x;
  const int bid = blockIdx.x;

  if (bid < 512) {
    const int wg = (bid & 7) * 64 + (bid >> 3);
    const int mt = wg >> 3, nt = wg & 7;
    const int m0 = mt * 128, n0 = nt * 64;

    const int w = t >> 6, lane = t & 63;
    const int wr = (w >> 1) * 64, wc = (w & 1) * 32;
    const int lr = lane & 15, lk = (lane >> 4) * 8;
    const int srow = (lane >> 3), scol = (lane & 7) * 8;

    f32x4 acc[4][2] = {};

    for (int ks = 0; ks < 8; ++ks) {
      const int k0 = ks * 64;
#pragma unroll
      for (int c = 0; c < 4; ++c) {
        const int ci = w * 4 + c;
        const u16* ga = A + (size_t)(m0 + ci * 8 + srow) * 512 + k0 + scol;
        __builtin_amdgcn_global_load_lds(
            (const __attribute__((address_space(1))) void*)ga,
            (__attribute__((address_space(3))) void*)&Al[ci * 8][0], 16, 0, 0);
      }
#pragma unroll
      for (int c = 0; c < 2; ++c) {
        const int ci = w * 2 + c;
        const u16* gb = Bw + (size_t)(n0 + ci * 8 + srow) * 512 + k0 + scol;
        __builtin_amdgcn_global_load_lds(
            (const __attribute__((address_space(1))) void*)gb,
            (__attribute__((address_space(3))) void*)&Bl[ci * 8][0], 16, 0, 0);
      }
      __syncthreads();
#pragma unroll
      for (int kk = 0; kk < 64; kk += 32) {
        bf16x8 af[4], bfr[2];
#pragma unroll
        for (int m = 0; m < 4; ++m)
          af[m] = *reinterpret_cast<const bf16x8*>(&Al[wr + m * 16 + lr][kk + lk]);
#pragma unroll
        for (int n = 0; n < 2; ++n)
          bfr[n] = *reinterpret_cast<const bf16x8*>(&Bl[wc + n * 16 + lr][kk + lk]);
#pragma unroll
        for (int m = 0; m < 4; ++m)
#pragma unroll
          for (int n = 0; n < 2; ++n)
            acc[m][n] = __builtin_amdgcn_mfma_f32_16x16x32_bf16(af[m], bfr[n], acc[m][n], 0, 0, 0);
      }
      __syncthreads();
    }

    const int rb = (lane >> 4) * 4;
#pragma unroll
    for (int m = 0; m < 4; ++m) {
#pragma unroll
      for (int n = 0; n < 2; ++n) {
#pragma unroll
        for (int r = 0; r < 4; ++r) {
          int row = m0 + wr + m * 16 + rb + r;
          int col = n0 + wc + n * 16 + lr;
          Of[(size_t)row * 512 + col] = acc[m][n][r] + bias[col];
        }
      }
    }
  } else {
    u16* band = &Al[0][0];                 // [4][8][80] u16 = 5 KB inside Al
    const int gr0 = (bid - 512) * 4;
    const int b = gr0 >> 11;
    const int i0 = gr0 & 2047;

    for (int s = t; s < 320; s += 256) {
      int ri = s / 80, rem = s - ri * 80;
      int h = rem / 10, c = rem - h * 10;
      const u16* src = pband + ((size_t)(b * 8 + h) * L_ + (i0 + ri)) * 80 + 8 * c;
      *reinterpret_cast<uint4*>(band + ri * 640 + h * 80 + 8 * c) =
          *reinterpret_cast<const uint4*>(src);
    }
    __syncthreads();

    const int c0 = t * 8;
#pragma unroll
    for (int ri = 0; ri < 4; ++ri) {
      const int i = i0 + ri;
      const int i15 = i & 15;
      float v[8];
#pragma unroll
      for (int k = 0; k < 8; ++k) {
        int col = c0 + k;
        int j = col - i + 32;
        float s = 0.f;
        if (j >= 0 && j <= 64) {
#pragma unroll
          for (int hh = 0; hh < 8; ++hh) s += b2f(band[ri * 640 + hh * 80 + j + i15]);
          s *= 0.125f;
        }
        v[k] = s;
      }
      float4* o = reinterpret_cast<float4*>(out1 + (size_t)(gr0 + ri) * L_ + c0);
      o[0] = make_float4(v[0], v[1], v[2], v[3]);
      o[1] = make_float4(v[4], v[5], v[6], v[7]);
    }
  }
}

extern "C" void kernel_launch(void* const* d_in, const int* in_sizes, int n_in,
                              void* d_out, int out_size, void* d_ws, size_t ws_size,
                              hipStream_t stream)
{
  const float* x  = (const float*)d_in[0];
  const float* Wq = (const float*)d_in[1]; const float* bq = (const float*)d_in[2];
  const float* Wk = (const float*)d_in[3]; const float* bk = (const float*)d_in[4];
  const float* Wv = (const float*)d_in[5]; const float* bv = (const float*)d_in[6];
  const float* Wo = (const float*)d_in[7]; const float* bo = (const float*)d_in[8];
  float* out0 = (float*)d_out;                       // [4,2048,512]
  float* out1 = out0 + (size_t)B_ * L_ * D_;         // [4,2048,2048]

  char* ws = (char*)d_ws;
  unsigned short* WQB = (unsigned short*)(ws +  8388608);      // Wq bf16 (Wk,Wv,Wo contiguous)
  unsigned short* WKB = (unsigned short*)(ws +  8912896);
  unsigned short* WVB = (unsigned short*)(ws +  9437184);
  unsigned short* WOB = (unsigned short*)(ws +  9961472);
  unsigned short* QB  = (unsigned short*)(ws + 10485760);      // Q,K,V [bh][l][dk] (8 MB each)
  unsigned short* KB  = (unsigned short*)(ws + 18874368);
  unsigned short* VB  = (unsigned short*)(ws + 27262976);
  unsigned short* AO  = (unsigned short*)(ws + 35651584);      // attn out bf16 8 MB
  unsigned short* PB  = (unsigned short*)(ws + 44040192);      // pband bf16 [65536][80] ~10.5 MB
  float*          BC  = (float*)        (ws + 54525952);       // fused bias [1536] f32

  cvt_w<<<1025, 256, 0, stream>>>(Wq, Wk, Wv, Wo, bq, bk, bv,
                                  WQB, WKB, WVB, WOB, BC);
  gemm_qkv<<<1536, 256, 0, stream>>>(x, WQB, BC, QB);
  attn_mfma<<<1024, 256, 0, stream>>>(QB, KB, VB, AO, PB);
  tail_fused<<<2560, 256, 0, stream>>>(AO, WOB, bo, out0, PB, out1);
}

// Round 20
// 66.470 us; speedup vs baseline: 1.0752x; 1.0752x over previous
//
#include <hip/hip_runtime.h>
#include <hip/hip_bf16.h>

#define B_ 4
#define L_ 2048
#define D_ 512
#define H_ 8
#define DK_ 64

typedef __bf16 bf16x8 __attribute__((ext_vector_type(8)));
typedef float f32x4 __attribute__((ext_vector_type(4)));
typedef unsigned short u16;
typedef unsigned short u16x8 __attribute__((ext_vector_type(8)));

template <bool V> struct BoolC { static constexpr bool value = V; };

__device__ __forceinline__ float b2f(unsigned short u) {
  union { unsigned int i; float f; } c; c.i = ((unsigned int)u) << 16; return c.f;
}
__device__ __forceinline__ unsigned short f2b(float f) {
  union { float f; unsigned int i; } c; c.f = f;
  unsigned int x = c.i;
  unsigned int r = x + 0x7fffu + ((x >> 16) & 1u);   // RNE
  return (unsigned short)(r >> 16);
}

// ---------------- fp32 -> bf16 convert: x + 4 weights + fused bias pack ----------------
__global__ __launch_bounds__(256) void cvt_all(
    const float* __restrict__ x,
    const float* __restrict__ W0, const float* __restrict__ W1,
    const float* __restrict__ W2, const float* __restrict__ W3,
    const float* __restrict__ bq, const float* __restrict__ bk, const float* __restrict__ bv,
    u16* __restrict__ XO,
    u16* __restrict__ O0, u16* __restrict__ O1, u16* __restrict__ O2, u16* __restrict__ O3,
    float* __restrict__ bcomb) {
  int bid = blockIdx.x;
  int t = threadIdx.x;
  if (bid == 5120) {                      // pack fused bias [1536]
#pragma unroll
    for (int e = 0; e < 6; ++e) {
      int idx = t + e * 256;
      float v = (idx < 512) ? bq[idx] : (idx < 1024) ? bk[idx - 512] : bv[idx - 1024];
      bcomb[idx] = v;
    }
    return;
  }
  const float* in;
  u16* out;
  int i;
  if (bid < 4096) {                       // x: 1,048,576 float4s
    in = x; out = XO; i = bid * 256 + t;
  } else {
    int z = (bid - 4096) >> 8;            // weights: 65,536 float4s each
    in  = (z == 0) ? W0 : (z == 1) ? W1 : (z == 2) ? W2 : W3;
    out = (z == 0) ? O0 : (z == 1) ? O1 : (z == 2) ? O2 : O3;
    i = ((bid - 4096) & 255) * 256 + t;
  }
  float4 v = reinterpret_cast<const float4*>(in)[i];
  ushort4 o;
  o.x = f2b(v.x); o.y = f2b(v.y); o.z = f2b(v.z); o.w = f2b(v.w);
  reinterpret_cast<ushort4*>(out)[i] = o;
}

// ---------------- fused QKV GEMM: [8192x512] @ [1536x512]^T + bias ----------------
// 64x128 tile, 1536 blocks, launch_bounds(256,6): 6 blocks/CU -> ONE residency round
// (was 5 -> rounds of 5+1 with a ragged 20%-fill tail). Q pre-scaled by 0.125 (exact).
__global__ __launch_bounds__(256, 6) void gemm_qkv(
    const u16* __restrict__ A, const u16* __restrict__ Bw,
    const float* __restrict__ bias, u16* __restrict__ QKVB)
{
  __shared__ __align__(16) u16 Al[64][64];
  __shared__ __align__(16) u16 Bl[128][64];
  const int t = threadIdx.x;
  // XCD swizzle: 1536 wgs = 8 xcds x 192
  const int wg = (blockIdx.x & 7) * 192 + (blockIdx.x >> 3);
  const int mt = wg / 12, nt = wg - mt * 12;
  const int m0 = mt * 64, n0c = nt * 128;
  const int z = n0c >> 9;
  u16* Obf = QKVB + (size_t)z * 4194304;

  const int w = t >> 6, lane = t & 63;
  const int wr = (w >> 1) * 32, wc = (w & 1) * 64;
  const int lr = lane & 15, lk = (lane >> 4) * 8;
  const int srow = (lane >> 3), scol = (lane & 7) * 8;

  f32x4 acc[2][4] = {};

  for (int ks = 0; ks < 8; ++ks) {
    const int k0 = ks * 64;
#pragma unroll
    for (int c = 0; c < 2; ++c) {         // A: 8 chunks, 2 per wave
      const int ci = w * 2 + c;
      const u16* ga = A + (size_t)(m0 + ci * 8 + srow) * 512 + k0 + scol;
      __builtin_amdgcn_global_load_lds(
          (const __attribute__((address_space(1))) void*)ga,
          (__attribute__((address_space(3))) void*)&Al[ci * 8][0], 16, 0, 0);
    }
#pragma unroll
    for (int c = 0; c < 4; ++c) {         // B: 16 chunks, 4 per wave
      const int ci = w * 4 + c;
      const u16* gb = Bw + (size_t)(n0c + ci * 8 + srow) * 512 + k0 + scol;
      __builtin_amdgcn_global_load_lds(
          (const __attribute__((address_space(1))) void*)gb,
          (__attribute__((address_space(3))) void*)&Bl[ci * 8][0], 16, 0, 0);
    }
    __syncthreads();
#pragma unroll
    for (int kk = 0; kk < 64; kk += 32) {
      bf16x8 af[2], bfr[4];
#pragma unroll
      for (int m = 0; m < 2; ++m)
        af[m] = *reinterpret_cast<const bf16x8*>(&Al[wr + m * 16 + lr][kk + lk]);
#pragma unroll
      for (int n = 0; n < 4; ++n)
        bfr[n] = *reinterpret_cast<const bf16x8*>(&Bl[wc + n * 16 + lr][kk + lk]);
#pragma unroll
      for (int m = 0; m < 2; ++m)
#pragma unroll
        for (int n = 0; n < 4; ++n)
          acc[m][n] = __builtin_amdgcn_mfma_f32_16x16x32_bf16(af[m], bfr[n], acc[m][n], 0, 0, 0);
    }
    __syncthreads();
  }

  const float qscale = (z == 0) ? 0.125f : 1.0f;     // block-uniform
  const int rb = (lane >> 4) * 4;
#pragma unroll
  for (int m = 0; m < 2; ++m) {
#pragma unroll
    for (int n = 0; n < 4; ++n) {
#pragma unroll
      for (int r = 0; r < 4; ++r) {
        int row = m0 + wr + m * 16 + rb + r;
        int colc = n0c + wc + n * 16 + lr;
        float v = (acc[m][n][r] + bias[colc]) * qscale;
        int b = row >> 11, l = row & 2047, h = (colc >> 6) & 7, dk = colc & 63;
        Obf[(((size_t)(b * 8 + h)) * 2048 + l) * 64 + dk] = f2b(v);
      }
    }
  }
}

// ---------------- windowed attention via MFMA (v5) ----------------
__global__ __launch_bounds__(256, 4) void attn_mfma(
    const u16* __restrict__ Qb, const u16* __restrict__ Kb, const u16* __restrict__ Vb,
    u16* __restrict__ AO,
    u16* __restrict__ pband)
{
  __shared__ __align__(16) u16 VT[64][136];
  __shared__ __align__(16) u16 Pl[4][16][104];
  __shared__ __align__(16) u16 Ol[4][16][72];

  const int t = threadIdx.x;
  const int blk = blockIdx.x;
  const int qt = blk & 31, bh = blk >> 5;
  const int b = bh >> 3, h = bh & 7;
  const int q0 = qt * 64;
  const int kbase0 = q0 - 32;
  const u16* Kp = Kb + (size_t)bh * L_ * 64;
  const u16* Vp = Vb + (size_t)bh * L_ * 64;
  const u16* Qp = Qb + (size_t)bh * L_ * 64;

  const int w = t >> 6, lane = t & 63;
  const int g = lane >> 4, ql16 = lane & 15;
  const int q = q0 + 16 * w + ql16;

  auto body = [&](auto edgec) {
    constexpr bool EDGE = decltype(edgec)::value;

    u16x8 vstage[4];
#pragma unroll
    for (int i = 0; i < 4; ++i) {
      int seg = i * 256 + t;
      int jb = seg >> 3, dk0 = (seg & 7) * 8;
      int src = kbase0 + jb;
      if (EDGE) src = src < 0 ? 0 : (src >= L_ ? L_ - 1 : src);
      vstage[i] = *reinterpret_cast<const u16x8*>(Vp + (size_t)src * 64 + dk0);
    }
    bf16x8 qf[2];
#pragma unroll
    for (int kc = 0; kc < 2; ++kc)
      qf[kc] = *reinterpret_cast<const bf16x8*>(Qp + (size_t)q * 64 + 32 * kc + 8 * g);

#pragma unroll
    for (int i = 0; i < 4; ++i) {
      int seg = i * 256 + t;
      int jb = seg >> 3, dk0 = (seg & 7) * 8;
      int jp = jb ^ dk0;
#pragma unroll
      for (int e = 0; e < 8; ++e)
        VT[dk0 + e][jp] = vstage[i][e];
    }

    bf16x8 kf[5][2];
#pragma unroll
    for (int f = 0; f < 5; ++f) {
      int row = kbase0 + 16 * w + 16 * f + ql16;
      if (EDGE) row = row < 0 ? 0 : (row >= L_ ? L_ - 1 : row);
#pragma unroll
      for (int kc = 0; kc < 2; ++kc)
        kf[f][kc] = *reinterpret_cast<const bf16x8*>(Kp + (size_t)row * 64 + 32 * kc + 8 * g);
    }

    f32x4 sacc[5] = {};
    __builtin_amdgcn_s_setprio(1);
#pragma unroll
    for (int kc = 0; kc < 2; ++kc)
#pragma unroll
      for (int f = 0; f < 5; ++f)
        sacc[f] = __builtin_amdgcn_mfma_f32_16x16x32_bf16(kf[f][kc], qf[kc], sacc[f], 0, 0, 0);
    __builtin_amdgcn_s_setprio(0);

    float mx = -1e30f;
#pragma unroll
    for (int f = 0; f < 5; ++f) {
#pragma unroll
      for (int r = 0; r < 4; ++r) {
        int jl = 16 * f + 4 * g + r;
        int jj = jl - ql16;
        bool valid;
        if constexpr (EDGE) {
          int key = kbase0 + 16 * w + jl;
          valid = (jj >= 0) && (jj <= 64) && (key >= 0) && (key < L_);
        } else {
          valid = (jj >= 0) && (jj <= 64);
        }
        float v = valid ? sacc[f][r] : -1e30f;
        sacc[f][r] = v;
        mx = fmaxf(mx, v);
      }
    }
    mx = fmaxf(mx, __shfl_xor(mx, 16, 64));
    mx = fmaxf(mx, __shfl_xor(mx, 32, 64));
    float den = 0.f;
#pragma unroll
    for (int f = 0; f < 5; ++f)
#pragma unroll
      for (int r = 0; r < 4; ++r) {
        float e = __expf(sacc[f][r] - mx);
        sacc[f][r] = e; den += e;
      }
    den += __shfl_xor(den, 16, 64);
    den += __shfl_xor(den, 32, 64);
    const float inv = 1.0f / den;

#pragma unroll
    for (int f = 0; f < 5; ++f) {
      ushort4 pk;
#pragma unroll
      for (int r = 0; r < 4; ++r)
        reinterpret_cast<u16*>(&pk)[r] = f2b(sacc[f][r] * inv);
      *reinterpret_cast<ushort4*>(&Pl[w][ql16][16 * f + 4 * g]) = pk;
    }
    {
      ushort4 z; z.x = z.y = z.z = z.w = 0;
      *reinterpret_cast<ushort4*>(&Pl[w][ql16][80 + 4 * g]) = z;
    }

    {
      u16* pbg = pband + ((size_t)bh * L_ + q0 + 16 * w) * 80;
#pragma unroll
      for (int i = 0; i < 3; ++i) {
        int seg = i * 64 + lane;
        if (seg < 160) {
          int r16 = seg / 10, c = seg - r16 * 10;
          *reinterpret_cast<uint4*>(pbg + (size_t)r16 * 80 + 8 * c) =
              *reinterpret_cast<const uint4*>(&Pl[w][r16][8 * c]);
        }
      }
    }

    __syncthreads();

    f32x4 oacc[4] = {};
    __builtin_amdgcn_s_setprio(1);
#pragma unroll
    for (int kc = 0; kc < 3; ++kc) {
      bf16x8 pf = *reinterpret_cast<const bf16x8*>(&Pl[w][ql16][32 * kc + 8 * g]);
#pragma unroll
      for (int m = 0; m < 4; ++m) {
        int dk = 16 * m + ql16;
        int jb = 16 * w + 32 * kc + 8 * g;
        if (jb > 120) jb = 120;
        bf16x8 vf = *reinterpret_cast<const bf16x8*>(&VT[dk][jb ^ (dk & 56)]);
        oacc[m] = __builtin_amdgcn_mfma_f32_16x16x32_bf16(vf, pf, oacc[m], 0, 0, 0);
      }
    }
    __builtin_amdgcn_s_setprio(0);

#pragma unroll
    for (int m = 0; m < 4; ++m) {
      ushort4 ok;
#pragma unroll
      for (int r = 0; r < 4; ++r) reinterpret_cast<u16*>(&ok)[r] = f2b(oacc[m][r]);
      *reinterpret_cast<ushort4*>(&Ol[w][ql16][16 * m + 4 * g]) = ok;
    }
#pragma unroll
    for (int i = 0; i < 2; ++i) {
      int seg = i * 64 + lane;
      int r16 = seg >> 3, ck = seg & 7;
      *reinterpret_cast<uint4*>(AO + ((size_t)(b * L_ + q0 + 16 * w + r16)) * 512 + h * 64 + ck * 8) =
          *reinterpret_cast<const uint4*>(&Ol[w][r16][ck * 8]);
    }
  };

  if (qt >= 1 && qt <= 30) body(BoolC<false>{});
  else body(BoolC<true>{});
}

// ---------------- fused tail: out-proj GEMM (512 blocks) + mean (2048 blocks) ----------------
__global__ __launch_bounds__(256, 4) void tail_fused(
    const u16* __restrict__ A,            // AO bf16 [8192][512]
    const u16* __restrict__ Bw,           // WOB bf16 [512][512]
    const float* __restrict__ bias,       // bo [512]
    float* __restrict__ Of,               // out0 [8192][512] f32
    const u16* __restrict__ pband,        // [B*H*L][80] bf16 (jl layout)
    float* __restrict__ out1)             // [B*L][2048] f32
{
  __shared__ __align__(16) u16 Al[128][64];
  __shared__ __align__(16) u16 Bl[64][64];
  const int t = threadIdx.x;
  const int bid = blockIdx.x;

  if (bid < 512) {
    const int wg = (bid & 7) * 64 + (bid >> 3);
    const int mt = wg >> 3, nt = wg & 7;
    const int m0 = mt * 128, n0 = nt * 64;

    const int w = t >> 6, lane = t & 63;
    const int wr = (w >> 1) * 64, wc = (w & 1) * 32;
    const int lr = lane & 15, lk = (lane >> 4) * 8;
    const int srow = (lane >> 3), scol = (lane & 7) * 8;

    f32x4 acc[4][2] = {};

    for (int ks = 0; ks < 8; ++ks) {
      const int k0 = ks * 64;
#pragma unroll
      for (int c = 0; c < 4; ++c) {
        const int ci = w * 4 + c;
        const u16* ga = A + (size_t)(m0 + ci * 8 + srow) * 512 + k0 + scol;
        __builtin_amdgcn_global_load_lds(
            (const __attribute__((address_space(1))) void*)ga,
            (__attribute__((address_space(3))) void*)&Al[ci * 8][0], 16, 0, 0);
      }
#pragma unroll
      for (int c = 0; c < 2; ++c) {
        const int ci = w * 2 + c;
        const u16* gb = Bw + (size_t)(n0 + ci * 8 + srow) * 512 + k0 + scol;
        __builtin_amdgcn_global_load_lds(
            (const __attribute__((address_space(1))) void*)gb,
            (__attribute__((address_space(3))) void*)&Bl[ci * 8][0], 16, 0, 0);
      }
      __syncthreads();
#pragma unroll
      for (int kk = 0; kk < 64; kk += 32) {
        bf16x8 af[4], bfr[2];
#pragma unroll
        for (int m = 0; m < 4; ++m)
          af[m] = *reinterpret_cast<const bf16x8*>(&Al[wr + m * 16 + lr][kk + lk]);
#pragma unroll
        for (int n = 0; n < 2; ++n)
          bfr[n] = *reinterpret_cast<const bf16x8*>(&Bl[wc + n * 16 + lr][kk + lk]);
#pragma unroll
        for (int m = 0; m < 4; ++m)
#pragma unroll
          for (int n = 0; n < 2; ++n)
            acc[m][n] = __builtin_amdgcn_mfma_f32_16x16x32_bf16(af[m], bfr[n], acc[m][n], 0, 0, 0);
      }
      __syncthreads();
    }

    const int rb = (lane >> 4) * 4;
#pragma unroll
    for (int m = 0; m < 4; ++m) {
#pragma unroll
      for (int n = 0; n < 2; ++n) {
#pragma unroll
        for (int r = 0; r < 4; ++r) {
          int row = m0 + wr + m * 16 + rb + r;
          int col = n0 + wc + n * 16 + lr;
          Of[(size_t)row * 512 + col] = acc[m][n][r] + bias[col];
        }
      }
    }
  } else {
    u16* band = &Al[0][0];                 // [4][8][80] u16 = 5 KB inside Al
    const int gr0 = (bid - 512) * 4;
    const int b = gr0 >> 11;
    const int i0 = gr0 & 2047;

    for (int s = t; s < 320; s += 256) {
      int ri = s / 80, rem = s - ri * 80;
      int h = rem / 10, c = rem - h * 10;
      const u16* src = pband + ((size_t)(b * 8 + h) * L_ + (i0 + ri)) * 80 + 8 * c;
      *reinterpret_cast<uint4*>(band + ri * 640 + h * 80 + 8 * c) =
          *reinterpret_cast<const uint4*>(src);
    }
    __syncthreads();

    const int c0 = t * 8;
#pragma unroll
    for (int ri = 0; ri < 4; ++ri) {
      const int i = i0 + ri;
      const int i15 = i & 15;
      float v[8];
#pragma unroll
      for (int k = 0; k < 8; ++k) {
        int col = c0 + k;
        int j = col - i + 32;
        float s = 0.f;
        if (j >= 0 && j <= 64) {
#pragma unroll
          for (int hh = 0; hh < 8; ++hh) s += b2f(band[ri * 640 + hh * 80 + j + i15]);
          s *= 0.125f;
        }
        v[k] = s;
      }
      float4* o = reinterpret_cast<float4*>(out1 + (size_t)(gr0 + ri) * L_ + c0);
      o[0] = make_float4(v[0], v[1], v[2], v[3]);
      o[1] = make_float4(v[4], v[5], v[6], v[7]);
    }
  }
}

extern "C" void kernel_launch(void* const* d_in, const int* in_sizes, int n_in,
                              void* d_out, int out_size, void* d_ws, size_t ws_size,
                              hipStream_t stream)
{
  const float* x  = (const float*)d_in[0];
  const float* Wq = (const float*)d_in[1]; const float* bq = (const float*)d_in[2];
  const float* Wk = (const float*)d_in[3]; const float* bk = (const float*)d_in[4];
  const float* Wv = (const float*)d_in[5]; const float* bv = (const float*)d_in[6];
  const float* Wo = (const float*)d_in[7]; const float* bo = (const float*)d_in[8];
  float* out0 = (float*)d_out;                       // [4,2048,512]
  float* out1 = out0 + (size_t)B_ * L_ * D_;         // [4,2048,2048]

  char* ws = (char*)d_ws;
  unsigned short* XB  = (unsigned short*)(ws);                 // x bf16        8 MB
  unsigned short* WQB = (unsigned short*)(ws +  8388608);      // Wq bf16 (Wk,Wv,Wo contiguous)
  unsigned short* WKB = (unsigned short*)(ws +  8912896);
  unsigned short* WVB = (unsigned short*)(ws +  9437184);
  unsigned short* WOB = (unsigned short*)(ws +  9961472);
  unsigned short* QB  = (unsigned short*)(ws + 10485760);      // Q,K,V [bh][l][dk] (8 MB each)
  unsigned short* KB  = (unsigned short*)(ws + 18874368);
  unsigned short* VB  = (unsigned short*)(ws + 27262976);
  unsigned short* AO  = (unsigned short*)(ws + 35651584);      // attn out bf16 8 MB
  unsigned short* PB  = (unsigned short*)(ws + 44040192);      // pband bf16 [65536][80] ~10.5 MB
  float*          BC  = (float*)        (ws + 54525952);       // fused bias [1536] f32

  cvt_all<<<5121, 256, 0, stream>>>(x, Wq, Wk, Wv, Wo, bq, bk, bv,
                                    XB, WQB, WKB, WVB, WOB, BC);
  gemm_qkv<<<1536, 256, 0, stream>>>(XB, WQB, BC, QB);
  attn_mfma<<<1024, 256, 0, stream>>>(QB, KB, VB, AO, PB);
  tail_fused<<<2560, 256, 0, stream>>>(AO, WOB, bo, out0, PB, out1);
}